// Round 2
// baseline (574.290 us; speedup 1.0000x reference)
//
#include <hip/hip_runtime.h>
#include <hip/hip_bf16.h>
#include <cstdint>

#define NCAMS 6
#define NQ 2500
#define EMBED 256
#define HEADS 8
#define DHEAD 32
#define NLVL 4
#define NPTS 8
#define LTOT 19560
#define MVAL (NCAMS * LTOT) /* 117360 */

// ---------------------------------------------------------------------------
// Kernel A: value projection  val[cam,h,l,d] = bf16( key_feats[cam,l,:] @ W_value[:,h*32+d] + b_value )
// Tiled f32 GEMM: 64x64 tile, 256 threads, 4x4 micro-tile.
// ---------------------------------------------------------------------------
__global__ __launch_bounds__(256) void k_valproj(
    const float* __restrict__ A,   // (117360, 256)
    const float* __restrict__ W,   // (256, 256)
    const float* __restrict__ bv,  // (256,)
    __hip_bfloat16* __restrict__ val) // (6, 8, 19560, 32)
{
  __shared__ float As[64][68]; // stored transposed: As[k][row]
  __shared__ float Bs[64][68]; // Bs[k][col]
  const int t  = threadIdx.x;
  const int bm = blockIdx.x * 64;
  const int bn = blockIdx.y * 64;
  const int tx = t & 15, ty = t >> 4;

  float acc[4][4] = {};
  for (int kk = 0; kk < 256; kk += 64) {
#pragma unroll
    for (int j = 0; j < 16; ++j) {
      int idx = j * 256 + t;
      int r = idx >> 6, c = idx & 63;
      int row = bm + r;
      As[c][r] = (row < MVAL) ? A[(size_t)row * 256 + kk + c] : 0.f;
      Bs[r][c] = W[(size_t)(kk + r) * 256 + bn + c];
    }
    __syncthreads();
#pragma unroll 8
    for (int k = 0; k < 64; ++k) {
      float4 a = *(const float4*)&As[k][ty * 4];
      float4 b = *(const float4*)&Bs[k][tx * 4];
      float av[4] = {a.x, a.y, a.z, a.w};
      float bw[4] = {b.x, b.y, b.z, b.w};
#pragma unroll
      for (int i = 0; i < 4; ++i)
#pragma unroll
        for (int j2 = 0; j2 < 4; ++j2) acc[i][j2] += av[i] * bw[j2];
    }
    __syncthreads();
  }

  float bcol[4];
#pragma unroll
  for (int j2 = 0; j2 < 4; ++j2) bcol[j2] = bv[bn + tx * 4 + j2];

#pragma unroll
  for (int i = 0; i < 4; ++i) {
    int row = bm + ty * 4 + i;
    if (row >= MVAL) continue;
    int cam = row / LTOT;
    int l   = row - cam * LTOT;
#pragma unroll
    for (int j2 = 0; j2 < 4; ++j2) {
      int col = bn + tx * 4 + j2;
      int h = col >> 5, d = col & 31;
      val[(size_t)(cam * HEADS + h) * (size_t)(LTOT * DHEAD) + (size_t)l * DHEAD + d] =
          __float2bfloat16(acc[i][j2] + bcol[j2]);
    }
  }
}

// ---------------------------------------------------------------------------
// Kernel B: OFF = q @ W_off + b_off   (2500,512)   [raw, un-normalized offsets]
//           LOG = q @ W_attn + b_attn (2500,256)
// ---------------------------------------------------------------------------
__global__ __launch_bounds__(256) void k_qproj(
    const float* __restrict__ Q,
    const float* __restrict__ Woff, const float* __restrict__ boff,
    const float* __restrict__ Wattn, const float* __restrict__ battn,
    float* __restrict__ OFF, float* __restrict__ LOG)
{
  __shared__ float qs[8][256];
  const int t  = threadIdx.x;
  const int q0 = blockIdx.x * 8;
#pragma unroll
  for (int j = 0; j < 8; ++j) {
    int qi = q0 + j;
    qs[j][t] = (qi < NQ) ? Q[(size_t)qi * 256 + t] : 0.f;
  }
  __syncthreads();

#pragma unroll 1
  for (int pass = 0; pass < 3; ++pass) {
    const float* W  = (pass < 2) ? Woff : Wattn;
    const float* bb = (pass < 2) ? boff : battn;
    const int nc = (pass < 2) ? 512 : 256;
    const int c  = (pass == 1) ? (256 + t) : t;
    float acc[8];
    float bc = bb[c];
#pragma unroll
    for (int j = 0; j < 8; ++j) acc[j] = bc;
    for (int k = 0; k < 256; k += 4) {
      float w0 = W[(size_t)k * nc + c];
      float w1 = W[(size_t)(k + 1) * nc + c];
      float w2 = W[(size_t)(k + 2) * nc + c];
      float w3 = W[(size_t)(k + 3) * nc + c];
#pragma unroll
      for (int j = 0; j < 8; ++j) {
        float4 qv = *(const float4*)&qs[j][k];
        acc[j] += qv.x * w0 + qv.y * w1 + qv.z * w2 + qv.w * w3;
      }
    }
#pragma unroll
    for (int j = 0; j < 8; ++j) {
      int qi = q0 + j;
      if (qi < NQ) {
        if (pass < 2) OFF[(size_t)qi * 512 + c] = acc[j];
        else          LOG[(size_t)qi * 256 + c] = acc[j];
      }
    }
  }
}

// ---------------------------------------------------------------------------
// Kernel M: bev_mask -> valid[6*2500] byte array, with on-device dtype detect.
// If mask arrives as int32 (bool upcast), all bytes at offset%4!=0 are zero.
// If it arrives as raw numpy bool (1B), ~30% of those bytes are nonzero.
// ---------------------------------------------------------------------------
__global__ __launch_bounds__(256) void k_maskvalid(
    const unsigned char* __restrict__ MSK,
    unsigned char* __restrict__ valid)
{
  __shared__ int s_u8;
  const int t = threadIdx.x;
  if (t == 0) s_u8 = 0;
  __syncthreads();
  if ((t & 3) && MSK[t]) atomicOr(&s_u8, 1);
  __syncthreads();
  const int isU8 = s_u8;

  const int i = blockIdx.x * 256 + t;
  if (i < NCAMS * NQ) {
    int any;
    if (isU8) {
      const unsigned char* p = MSK + (size_t)i * 4;
      any = p[0] | p[1] | p[2] | p[3];
    } else {
      const int* p = (const int*)MSK + (size_t)i * 4;
      any = p[0] | p[1] | p[2] | p[3];
    }
    valid[i] = any ? 1 : 0;
  }
}

// ---------------------------------------------------------------------------
// Kernel C: per-query softmax + deformable sampling + camera aggregation.
// One block per query; 256 threads = 8 heads x 32 dims.
// x = ref_x*W + off_raw_x - 0.5  (norm division cancels with *W)
// ---------------------------------------------------------------------------
__global__ __launch_bounds__(256) void k_sample(
    const __hip_bfloat16* __restrict__ val,
    const float* __restrict__ OFF, const float* __restrict__ LOG,
    const float* __restrict__ REF,            // (6,1,2500,4,2)
    const unsigned char* __restrict__ valid,  // (6,2500)
    float* __restrict__ slots)                // (2500,256)
{
  __shared__ float s_off[512];
  __shared__ float s_aw[256];
  __shared__ float s_ref[48];
  __shared__ int   s_valid[6];

  const int q = blockIdx.x;
  const int t = threadIdx.x;
  const int h = t >> 5, d = t & 31;

  s_off[t]       = OFF[(size_t)q * 512 + t];
  s_off[t + 256] = OFF[(size_t)q * 512 + 256 + t];
  if (t < 48) s_ref[t] = REF[(size_t)(t >> 3) * (NQ * 8) + (size_t)q * 8 + (t & 7)];
  if (t < 6) s_valid[t] = valid[(size_t)t * NQ + q];

  // softmax over 32 logits per head
  float logit = LOG[(size_t)q * 256 + t];
  float m = logit;
#pragma unroll
  for (int o = 16; o > 0; o >>= 1) m = fmaxf(m, __shfl_xor(m, o, 32));
  float e = __expf(logit - m);
  float s = e;
#pragma unroll
  for (int o = 16; o > 0; o >>= 1) s += __shfl_xor(s, o, 32);
  s_aw[t] = e / s;
  __syncthreads();

  int nvalid = s_valid[0] + s_valid[1] + s_valid[2] + s_valid[3] + s_valid[4] + s_valid[5];
  float inv = 1.f / fmaxf((float)nvalid, 1.f);

  constexpr int Hs[4] = {92, 46, 23, 12};
  constexpr int Wls[4] = {160, 80, 40, 20};
  constexpr int Ss[4] = {0, 14720, 18400, 19320};

  float acc = 0.f;
  for (int cam = 0; cam < NCAMS; ++cam) {
    if (!s_valid[cam]) continue;
    const __hip_bfloat16* vc =
        val + (size_t)(cam * HEADS + h) * (size_t)(LTOT * DHEAD) + d;
#pragma unroll
    for (int lvl = 0; lvl < 4; ++lvl) {
      const int HH = Hs[lvl], WW = Wls[lvl];
      const float Hf = (float)HH, Wf = (float)WW;
      const __hip_bfloat16* vl = vc + (size_t)Ss[lvl] * DHEAD;
#pragma unroll
      for (int p = 0; p < 8; ++p) {
        int z = p & 3;
        float rx = s_ref[cam * 8 + z * 2];
        float ry = s_ref[cam * 8 + z * 2 + 1];
        float ox = s_off[h * 64 + lvl * 16 + p * 2];
        float oy = s_off[h * 64 + lvl * 16 + p * 2 + 1];
        float a  = s_aw[h * 32 + lvl * 8 + p];
        float x = rx * Wf + ox - 0.5f;
        float y = ry * Hf + oy - 0.5f;
        float x0f = floorf(x), y0f = floorf(y);
        float fx = x - x0f, fy = y - y0f;
        int x0 = (int)x0f, y0 = (int)y0f;
#pragma unroll
        for (int dy = 0; dy < 2; ++dy) {
          int yi = y0 + dy;
          float wy = dy ? fy : 1.f - fy;
          int yc = min(max(yi, 0), HH - 1);
          bool vy = (yi >= 0) && (yi < HH);
#pragma unroll
          for (int dx = 0; dx < 2; ++dx) {
            int xi = x0 + dx;
            float wx = dx ? fx : 1.f - fx;
            int xc = min(max(xi, 0), WW - 1);
            bool vv = vy && (xi >= 0) && (xi < WW);
            float cw = vv ? wx * wy * a : 0.f;
            float g = __bfloat162float(vl[(size_t)(yc * WW + xc) * DHEAD]);
            acc += cw * g;
          }
        }
      }
    }
  }
  slots[(size_t)q * 256 + t] = acc * inv;
}

// ---------------------------------------------------------------------------
// Kernel D: out = slots @ W_out + b_out + query
// ---------------------------------------------------------------------------
__global__ __launch_bounds__(256) void k_outproj(
    const float* __restrict__ S, const float* __restrict__ Wout,
    const float* __restrict__ bout, const float* __restrict__ Q,
    float* __restrict__ out)
{
  __shared__ float ss[8][256];
  const int t  = threadIdx.x;
  const int q0 = blockIdx.x * 8;
#pragma unroll
  for (int j = 0; j < 8; ++j) {
    int qi = q0 + j;
    ss[j][t] = (qi < NQ) ? S[(size_t)qi * 256 + t] : 0.f;
  }
  __syncthreads();
  float acc[8] = {};
  for (int k = 0; k < 256; k += 4) {
    float w0 = Wout[(size_t)k * 256 + t];
    float w1 = Wout[(size_t)(k + 1) * 256 + t];
    float w2 = Wout[(size_t)(k + 2) * 256 + t];
    float w3 = Wout[(size_t)(k + 3) * 256 + t];
#pragma unroll
    for (int j = 0; j < 8; ++j) {
      float4 sv = *(const float4*)&ss[j][k];
      acc[j] += sv.x * w0 + sv.y * w1 + sv.z * w2 + sv.w * w3;
    }
  }
  float bc = bout[t];
#pragma unroll
  for (int j = 0; j < 8; ++j) {
    int qi = q0 + j;
    if (qi < NQ) out[(size_t)qi * 256 + t] = acc[j] + bc + Q[(size_t)qi * 256 + t];
  }
}

// ---------------------------------------------------------------------------
extern "C" void kernel_launch(void* const* d_in, const int* in_sizes, int n_in,
                              void* d_out, int out_size, void* d_ws, size_t ws_size,
                              hipStream_t stream) {
  const float* query     = (const float*)d_in[0];
  const float* key_feats = (const float*)d_in[1];
  const float* ref       = (const float*)d_in[2];
  const unsigned char* mask = (const unsigned char*)d_in[3];
  // d_in[4] = spatial_shapes (compile-time constants)
  const float* Wv    = (const float*)d_in[5];
  const float* bv    = (const float*)d_in[6];
  const float* Woff  = (const float*)d_in[7];
  const float* boff  = (const float*)d_in[8];
  const float* Wattn = (const float*)d_in[9];
  const float* battn = (const float*)d_in[10];
  const float* Wout  = (const float*)d_in[11];
  const float* bout  = (const float*)d_in[12];
  float* out = (float*)d_out;

  char* ws = (char*)d_ws;
  __hip_bfloat16* val = (__hip_bfloat16*)ws;                       // 60,088,320 B
  float* OFF   = (float*)(ws + 60088320);                          //  5,120,000 B
  float* LOG   = (float*)(ws + 60088320 + 5120000);                //  2,560,000 B
  float* slots = (float*)(ws + 60088320 + 5120000 + 2560000);      //  2,560,000 B
  unsigned char* valid = (unsigned char*)(ws + 60088320 + 5120000 + 2560000 + 2560000); // 15,000 B

  hipLaunchKernelGGL(k_valproj, dim3((MVAL + 63) / 64, 4), dim3(256), 0, stream,
                     key_feats, Wv, bv, val);
  hipLaunchKernelGGL(k_qproj, dim3((NQ + 7) / 8), dim3(256), 0, stream,
                     query, Woff, boff, Wattn, battn, OFF, LOG);
  hipLaunchKernelGGL(k_maskvalid, dim3((NCAMS * NQ + 255) / 256), dim3(256), 0, stream,
                     mask, valid);
  hipLaunchKernelGGL(k_sample, dim3(NQ), dim3(256), 0, stream,
                     val, OFF, LOG, ref, valid, slots);
  hipLaunchKernelGGL(k_outproj, dim3((NQ + 7) / 8), dim3(256), 0, stream,
                     slots, Wout, bout, query, out);
}

// Round 3
// 374.486 us; speedup vs baseline: 1.5335x; 1.5335x over previous
//
#include <hip/hip_runtime.h>
#include <hip/hip_bf16.h>
#include <cstdint>

#define NCAMS 6
#define NQ 2500
#define EMBED 256
#define HEADS 8
#define DHEAD 32
#define LTOT 19560
#define MVAL (NCAMS * LTOT) /* 117360 */

typedef __attribute__((ext_vector_type(8))) short bf16x8;
typedef __attribute__((ext_vector_type(4))) float f32x4;

__device__ __forceinline__ unsigned short f2bf(float f) {
  unsigned u = __float_as_uint(f);
  return (unsigned short)((u + 0x7fffu + ((u >> 16) & 1u)) >> 16);
}
__device__ __forceinline__ float bf2f(unsigned short h) {
  return __uint_as_float(((unsigned)h) << 16);
}

// ---------------------------------------------------------------------------
// Kernel W: WT[c][k] = bf16(W_value[k][c])   (256x256)
// ---------------------------------------------------------------------------
__global__ __launch_bounds__(256) void k_wprep(
    const float* __restrict__ W, unsigned short* __restrict__ WT)
{
  const int c = blockIdx.x, t = threadIdx.x;
  WT[(size_t)c * 256 + t] = f2bf(W[(size_t)t * 256 + c]);
}

// ---------------------------------------------------------------------------
// Kernel A: val[row][col] = bf16( A[row][:] @ W[:,col] + bv[col] )
// row = cam*LTOT + l, col = h*32+d.  MFMA bf16 16x16x32.
// 512 threads = 8 waves (2 M x 4 N), BM=128, BN=256, BK=64.
// LDS tiles [rows][64] bf16 with XOR swizzle: elem = row*64 + ((k>>3)^(row&7))*8 + (k&7)
// ---------------------------------------------------------------------------
__global__ __launch_bounds__(512, 2) void k_valproj_mfma(
    const float* __restrict__ A,            // (117360, 256) f32
    const unsigned short* __restrict__ WT,  // (256 cols, 256 k) bf16
    const float* __restrict__ bv,           // (256,)
    unsigned short* __restrict__ val)       // (117360, 256) bf16
{
  __shared__ unsigned short As[128 * 64];
  __shared__ unsigned short Bs[256 * 64];
  const int t = threadIdx.x;
  const int lane = t & 63;
  const int wid = t >> 6;
  const int wm = wid >> 2, wn = wid & 3;
  const int laneM = lane & 15, kGrp = lane >> 4;
  const int bm = blockIdx.x * 128;

  const int aG = t & 15, aR0 = t >> 4;  // A: 16 float4-groups/row, 32 rows/pass
  const int bC = t & 7,  bR0 = t >> 3;  // B: 8 16B-chunks/row, 64 rows/pass

  float4 aRegs[2][4];
  uint4  bRegs[2][4];
  f32x4  acc[4][4];
#pragma unroll
  for (int m = 0; m < 4; ++m)
#pragma unroll
    for (int n = 0; n < 4; ++n) acc[m][n] = {0.f, 0.f, 0.f, 0.f};

  // prologue: load K-step 0
#pragma unroll
  for (int p = 0; p < 4; ++p) {
    int row = bm + aR0 + p * 32;
    aRegs[0][p] = (row < MVAL) ? *(const float4*)&A[(size_t)row * 256 + aG * 4]
                               : make_float4(0.f, 0.f, 0.f, 0.f);
    bRegs[0][p] = *(const uint4*)&WT[(size_t)(bR0 + p * 64) * 256 + bC * 8];
  }

#pragma unroll
  for (int kk = 0; kk < 4; ++kk) {
    const int cur = kk & 1, nxt = cur ^ 1;
    if (kk) __syncthreads();  // previous compute done reading LDS
    // ---- store staged regs -> LDS (convert A to bf16), swizzled ----
#pragma unroll
    for (int p = 0; p < 4; ++p) {
      int row = aR0 + p * 32;
      int elem = row * 64 + (((aG >> 1) ^ (row & 7)) << 3) + (aG & 1) * 4;
      float4 a = aRegs[cur][p];
      uint2 u;
      u.x = (unsigned)f2bf(a.x) | ((unsigned)f2bf(a.y) << 16);
      u.y = (unsigned)f2bf(a.z) | ((unsigned)f2bf(a.w) << 16);
      *(uint2*)&As[elem] = u;
    }
#pragma unroll
    for (int p = 0; p < 4; ++p) {
      int row = bR0 + p * 64;
      int elem = row * 64 + ((bC ^ (row & 7)) << 3);
      *(uint4*)&Bs[elem] = bRegs[cur][p];
    }
    __syncthreads();
    // ---- prefetch next K-step into the other reg set ----
    if (kk < 3) {
      const int kn = (kk + 1) * 64;
#pragma unroll
      for (int p = 0; p < 4; ++p) {
        int row = bm + aR0 + p * 32;
        aRegs[nxt][p] = (row < MVAL)
            ? *(const float4*)&A[(size_t)row * 256 + kn + aG * 4]
            : make_float4(0.f, 0.f, 0.f, 0.f);
        bRegs[nxt][p] = *(const uint4*)&WT[(size_t)(bR0 + p * 64) * 256 + kn + bC * 8];
      }
    }
    // ---- MFMA on current LDS tiles ----
#pragma unroll
    for (int ks = 0; ks < 2; ++ks) {
      bf16x8 af[4], bfr[4];
#pragma unroll
      for (int m = 0; m < 4; ++m) {
        int row = wm * 64 + m * 16 + laneM;
        af[m] = *(bf16x8*)&As[row * 64 + (((ks * 4 + kGrp) ^ (row & 7)) << 3)];
      }
#pragma unroll
      for (int n = 0; n < 4; ++n) {
        int row = wn * 64 + n * 16 + laneM;
        bfr[n] = *(bf16x8*)&Bs[row * 64 + (((ks * 4 + kGrp) ^ (row & 7)) << 3)];
      }
#pragma unroll
      for (int m = 0; m < 4; ++m)
#pragma unroll
        for (int n = 0; n < 4; ++n)
          acc[m][n] = __builtin_amdgcn_mfma_f32_16x16x32_bf16(af[m], bfr[n], acc[m][n], 0, 0, 0);
    }
  }

  // ---- epilogue: C/D layout col=lane&15, row=(lane>>4)*4+r ----
  float bvn[4];
#pragma unroll
  for (int n = 0; n < 4; ++n) bvn[n] = bv[wn * 64 + n * 16 + laneM];
#pragma unroll
  for (int m = 0; m < 4; ++m) {
#pragma unroll
    for (int r = 0; r < 4; ++r) {
      int row = bm + wm * 64 + m * 16 + kGrp * 4 + r;
      if (row < MVAL) {
#pragma unroll
        for (int n = 0; n < 4; ++n) {
          int col = wn * 64 + n * 16 + laneM;
          val[(size_t)row * 256 + col] = f2bf(acc[m][n][r] + bvn[n]);
        }
      }
    }
  }
}

// ---------------------------------------------------------------------------
// Kernel B: OFF = q @ W_off + b_off (2500,512); LOG = q @ W_attn + b_attn (2500,256)
// ---------------------------------------------------------------------------
__global__ __launch_bounds__(256) void k_qproj(
    const float* __restrict__ Q,
    const float* __restrict__ Woff, const float* __restrict__ boff,
    const float* __restrict__ Wattn, const float* __restrict__ battn,
    float* __restrict__ OFF, float* __restrict__ LOG)
{
  __shared__ float qs[8][256];
  const int t  = threadIdx.x;
  const int q0 = blockIdx.x * 8;
#pragma unroll
  for (int j = 0; j < 8; ++j) {
    int qi = q0 + j;
    qs[j][t] = (qi < NQ) ? Q[(size_t)qi * 256 + t] : 0.f;
  }
  __syncthreads();

#pragma unroll 1
  for (int pass = 0; pass < 3; ++pass) {
    const float* W  = (pass < 2) ? Woff : Wattn;
    const float* bb = (pass < 2) ? boff : battn;
    const int nc = (pass < 2) ? 512 : 256;
    const int c  = (pass == 1) ? (256 + t) : t;
    float acc[8];
    float bc = bb[c];
#pragma unroll
    for (int j = 0; j < 8; ++j) acc[j] = bc;
    for (int k = 0; k < 256; k += 4) {
      float w0 = W[(size_t)k * nc + c];
      float w1 = W[(size_t)(k + 1) * nc + c];
      float w2 = W[(size_t)(k + 2) * nc + c];
      float w3 = W[(size_t)(k + 3) * nc + c];
#pragma unroll
      for (int j = 0; j < 8; ++j) {
        float4 qv = *(const float4*)&qs[j][k];
        acc[j] += qv.x * w0 + qv.y * w1 + qv.z * w2 + qv.w * w3;
      }
    }
#pragma unroll
    for (int j = 0; j < 8; ++j) {
      int qi = q0 + j;
      if (qi < NQ) {
        if (pass < 2) OFF[(size_t)qi * 512 + c] = acc[j];
        else          LOG[(size_t)qi * 256 + c] = acc[j];
      }
    }
  }
}

// ---------------------------------------------------------------------------
// Kernel M: bev_mask -> valid[6*2500], on-device dtype detect (int32 vs u8).
// ---------------------------------------------------------------------------
__global__ __launch_bounds__(256) void k_maskvalid(
    const unsigned char* __restrict__ MSK,
    unsigned char* __restrict__ valid)
{
  __shared__ int s_u8;
  const int t = threadIdx.x;
  if (t == 0) s_u8 = 0;
  __syncthreads();
  if ((t & 3) && MSK[t]) atomicOr(&s_u8, 1);
  __syncthreads();
  const int isU8 = s_u8;

  const int i = blockIdx.x * 256 + t;
  if (i < NCAMS * NQ) {
    int any;
    if (isU8) {
      const unsigned char* p = MSK + (size_t)i * 4;
      any = p[0] | p[1] | p[2] | p[3];
    } else {
      const int* p = (const int*)MSK + (size_t)i * 4;
      any = p[0] | p[1] | p[2] | p[3];
    }
    valid[i] = any ? 1 : 0;
  }
}

// ---------------------------------------------------------------------------
// Kernel C: softmax + deformable sampling + camera aggregation.
// One block per query; 256 threads = 8 heads x 32 dims.
// val layout: (cam*LTOT + l, 256) with col = h*32+d.
// ---------------------------------------------------------------------------
__global__ __launch_bounds__(256) void k_sample(
    const unsigned short* __restrict__ val,
    const float* __restrict__ OFF, const float* __restrict__ LOG,
    const float* __restrict__ REF,            // (6,1,2500,4,2)
    const unsigned char* __restrict__ valid,  // (6,2500)
    float* __restrict__ slots)                // (2500,256)
{
  __shared__ float s_off[512];
  __shared__ float s_aw[256];
  __shared__ float s_ref[48];
  __shared__ int   s_valid[6];

  const int q = blockIdx.x;
  const int t = threadIdx.x;
  const int h = t >> 5, d = t & 31;

  s_off[t]       = OFF[(size_t)q * 512 + t];
  s_off[t + 256] = OFF[(size_t)q * 512 + 256 + t];
  if (t < 48) s_ref[t] = REF[(size_t)(t >> 3) * (NQ * 8) + (size_t)q * 8 + (t & 7)];
  if (t < 6) s_valid[t] = valid[(size_t)t * NQ + q];

  float logit = LOG[(size_t)q * 256 + t];
  float m = logit;
#pragma unroll
  for (int o = 16; o > 0; o >>= 1) m = fmaxf(m, __shfl_xor(m, o, 32));
  float e = __expf(logit - m);
  float s = e;
#pragma unroll
  for (int o = 16; o > 0; o >>= 1) s += __shfl_xor(s, o, 32);
  s_aw[t] = e / s;
  __syncthreads();

  int nvalid = s_valid[0] + s_valid[1] + s_valid[2] + s_valid[3] + s_valid[4] + s_valid[5];
  float inv = 1.f / fmaxf((float)nvalid, 1.f);

  constexpr int Hs[4] = {92, 46, 23, 12};
  constexpr int Wls[4] = {160, 80, 40, 20};
  constexpr int Ss[4] = {0, 14720, 18400, 19320};

  float acc = 0.f;
  for (int cam = 0; cam < NCAMS; ++cam) {
    if (!s_valid[cam]) continue;
    const unsigned short* vc = val + (size_t)cam * LTOT * 256 + h * 32 + d;
#pragma unroll
    for (int lvl = 0; lvl < 4; ++lvl) {
      const int HH = Hs[lvl], WW = Wls[lvl];
      const float Hf = (float)HH, Wf = (float)WW;
      const unsigned short* vl = vc + (size_t)Ss[lvl] * 256;
#pragma unroll
      for (int p = 0; p < 8; ++p) {
        int z = p & 3;
        float rx = s_ref[cam * 8 + z * 2];
        float ry = s_ref[cam * 8 + z * 2 + 1];
        float ox = s_off[h * 64 + lvl * 16 + p * 2];
        float oy = s_off[h * 64 + lvl * 16 + p * 2 + 1];
        float a  = s_aw[h * 32 + lvl * 8 + p];
        float x = rx * Wf + ox - 0.5f;
        float y = ry * Hf + oy - 0.5f;
        float x0f = floorf(x), y0f = floorf(y);
        float fx = x - x0f, fy = y - y0f;
        int x0 = (int)x0f, y0 = (int)y0f;
#pragma unroll
        for (int dy = 0; dy < 2; ++dy) {
          int yi = y0 + dy;
          float wy = dy ? fy : 1.f - fy;
          int yc = min(max(yi, 0), HH - 1);
          bool vy = (yi >= 0) && (yi < HH);
#pragma unroll
          for (int dx = 0; dx < 2; ++dx) {
            int xi = x0 + dx;
            float wx = dx ? fx : 1.f - fx;
            int xc = min(max(xi, 0), WW - 1);
            bool vv = vy && (xi >= 0) && (xi < WW);
            float cw = vv ? wx * wy * a : 0.f;
            float g = bf2f(vl[(size_t)(yc * WW + xc) * 256]);
            acc += cw * g;
          }
        }
      }
    }
  }
  slots[(size_t)q * 256 + t] = acc * inv;
}

// ---------------------------------------------------------------------------
// Kernel D: out = slots @ W_out + b_out + query
// ---------------------------------------------------------------------------
__global__ __launch_bounds__(256) void k_outproj(
    const float* __restrict__ S, const float* __restrict__ Wout,
    const float* __restrict__ bout, const float* __restrict__ Q,
    float* __restrict__ out)
{
  __shared__ float ss[8][256];
  const int t  = threadIdx.x;
  const int q0 = blockIdx.x * 8;
#pragma unroll
  for (int j = 0; j < 8; ++j) {
    int qi = q0 + j;
    ss[j][t] = (qi < NQ) ? S[(size_t)qi * 256 + t] : 0.f;
  }
  __syncthreads();
  float acc[8] = {};
  for (int k = 0; k < 256; k += 4) {
    float w0 = Wout[(size_t)k * 256 + t];
    float w1 = Wout[(size_t)(k + 1) * 256 + t];
    float w2 = Wout[(size_t)(k + 2) * 256 + t];
    float w3 = Wout[(size_t)(k + 3) * 256 + t];
#pragma unroll
    for (int j = 0; j < 8; ++j) {
      float4 sv = *(const float4*)&ss[j][k];
      acc[j] += sv.x * w0 + sv.y * w1 + sv.z * w2 + sv.w * w3;
    }
  }
  float bc = bout[t];
#pragma unroll
  for (int j = 0; j < 8; ++j) {
    int qi = q0 + j;
    if (qi < NQ) out[(size_t)qi * 256 + t] = acc[j] + bc + Q[(size_t)qi * 256 + t];
  }
}

// ---------------------------------------------------------------------------
extern "C" void kernel_launch(void* const* d_in, const int* in_sizes, int n_in,
                              void* d_out, int out_size, void* d_ws, size_t ws_size,
                              hipStream_t stream) {
  const float* query     = (const float*)d_in[0];
  const float* key_feats = (const float*)d_in[1];
  const float* ref       = (const float*)d_in[2];
  const unsigned char* mask = (const unsigned char*)d_in[3];
  // d_in[4] = spatial_shapes (compile-time constants)
  const float* Wv    = (const float*)d_in[5];
  const float* bv    = (const float*)d_in[6];
  const float* Woff  = (const float*)d_in[7];
  const float* boff  = (const float*)d_in[8];
  const float* Wattn = (const float*)d_in[9];
  const float* battn = (const float*)d_in[10];
  const float* Wout  = (const float*)d_in[11];
  const float* bout  = (const float*)d_in[12];
  float* out = (float*)d_out;

  char* ws = (char*)d_ws;
  size_t off = 0;
  unsigned short* val = (unsigned short*)(ws + off); off += (size_t)MVAL * 256 * 2; // 60,088,320
  unsigned short* WT  = (unsigned short*)(ws + off); off += 256 * 256 * 2;          //    131,072
  float* OFF   = (float*)(ws + off); off += (size_t)NQ * 512 * 4;                   //  5,120,000
  float* LOG   = (float*)(ws + off); off += (size_t)NQ * 256 * 4;                   //  2,560,000
  float* slots = (float*)(ws + off); off += (size_t)NQ * 256 * 4;                   //  2,560,000
  unsigned char* valid = (unsigned char*)(ws + off); off += NCAMS * NQ;             //     15,000

  hipLaunchKernelGGL(k_wprep, dim3(256), dim3(256), 0, stream, Wv, WT);
  hipLaunchKernelGGL(k_valproj_mfma, dim3((MVAL + 127) / 128), dim3(512), 0, stream,
                     key_feats, WT, bv, val);
  hipLaunchKernelGGL(k_qproj, dim3((NQ + 7) / 8), dim3(256), 0, stream,
                     query, Woff, boff, Wattn, battn, OFF, LOG);
  hipLaunchKernelGGL(k_maskvalid, dim3((NCAMS * NQ + 255) / 256), dim3(256), 0, stream,
                     mask, valid);
  hipLaunchKernelGGL(k_sample, dim3(NQ), dim3(256), 0, stream,
                     val, OFF, LOG, ref, valid, slots);
  hipLaunchKernelGGL(k_outproj, dim3((NQ + 7) / 8), dim3(256), 0, stream,
                     slots, Wout, bout, query, out);
}

// Round 4
// 272.825 us; speedup vs baseline: 2.1050x; 1.3726x over previous
//
#include <hip/hip_runtime.h>
#include <hip/hip_bf16.h>
#include <cstdint>

#define NCAMS 6
#define NQ 2500
#define EMBED 256
#define HEADS 8
#define DHEAD 32
#define LTOT 19560
#define MVAL (NCAMS * LTOT) /* 117360 */

typedef __attribute__((ext_vector_type(8))) short bf16x8;
typedef __attribute__((ext_vector_type(4))) float f32x4;

__device__ __forceinline__ unsigned short f2bf(float f) {
  unsigned u = __float_as_uint(f);
  return (unsigned short)((u + 0x7fffu + ((u >> 16) & 1u)) >> 16);
}
__device__ __forceinline__ float bf2f(unsigned short h) {
  return __uint_as_float(((unsigned)h) << 16);
}

// ---------------------------------------------------------------------------
// Kernel W: WT[c][k] = bf16(W_value[k][c])   (256x256)
// ---------------------------------------------------------------------------
__global__ __launch_bounds__(256) void k_wprep(
    const float* __restrict__ W, unsigned short* __restrict__ WT)
{
  const int c = blockIdx.x, t = threadIdx.x;
  WT[(size_t)c * 256 + t] = f2bf(W[(size_t)t * 256 + c]);
}

// ---------------------------------------------------------------------------
// Kernel A: val[row][col] = bf16( A[row][:] @ W[:,col] + bv[col] )  (MFMA)
// ---------------------------------------------------------------------------
__global__ __launch_bounds__(512, 2) void k_valproj_mfma(
    const float* __restrict__ A,            // (117360, 256) f32
    const unsigned short* __restrict__ WT,  // (256 cols, 256 k) bf16
    const float* __restrict__ bv,           // (256,)
    unsigned short* __restrict__ val)       // (117360, 256) bf16
{
  __shared__ unsigned short As[128 * 64];
  __shared__ unsigned short Bs[256 * 64];
  const int t = threadIdx.x;
  const int lane = t & 63;
  const int wid = t >> 6;
  const int wm = wid >> 2, wn = wid & 3;
  const int laneM = lane & 15, kGrp = lane >> 4;
  const int bm = blockIdx.x * 128;

  const int aG = t & 15, aR0 = t >> 4;
  const int bC = t & 7,  bR0 = t >> 3;

  float4 aRegs[2][4];
  uint4  bRegs[2][4];
  f32x4  acc[4][4];
#pragma unroll
  for (int m = 0; m < 4; ++m)
#pragma unroll
    for (int n = 0; n < 4; ++n) acc[m][n] = {0.f, 0.f, 0.f, 0.f};

#pragma unroll
  for (int p = 0; p < 4; ++p) {
    int row = bm + aR0 + p * 32;
    aRegs[0][p] = (row < MVAL) ? *(const float4*)&A[(size_t)row * 256 + aG * 4]
                               : make_float4(0.f, 0.f, 0.f, 0.f);
    bRegs[0][p] = *(const uint4*)&WT[(size_t)(bR0 + p * 64) * 256 + bC * 8];
  }

#pragma unroll
  for (int kk = 0; kk < 4; ++kk) {
    const int cur = kk & 1, nxt = cur ^ 1;
    if (kk) __syncthreads();
#pragma unroll
    for (int p = 0; p < 4; ++p) {
      int row = aR0 + p * 32;
      int elem = row * 64 + (((aG >> 1) ^ (row & 7)) << 3) + (aG & 1) * 4;
      float4 a = aRegs[cur][p];
      uint2 u;
      u.x = (unsigned)f2bf(a.x) | ((unsigned)f2bf(a.y) << 16);
      u.y = (unsigned)f2bf(a.z) | ((unsigned)f2bf(a.w) << 16);
      *(uint2*)&As[elem] = u;
    }
#pragma unroll
    for (int p = 0; p < 4; ++p) {
      int row = bR0 + p * 64;
      int elem = row * 64 + ((bC ^ (row & 7)) << 3);
      *(uint4*)&Bs[elem] = bRegs[cur][p];
    }
    __syncthreads();
    if (kk < 3) {
      const int kn = (kk + 1) * 64;
#pragma unroll
      for (int p = 0; p < 4; ++p) {
        int row = bm + aR0 + p * 32;
        aRegs[nxt][p] = (row < MVAL)
            ? *(const float4*)&A[(size_t)row * 256 + kn + aG * 4]
            : make_float4(0.f, 0.f, 0.f, 0.f);
        bRegs[nxt][p] = *(const uint4*)&WT[(size_t)(bR0 + p * 64) * 256 + kn + bC * 8];
      }
    }
#pragma unroll
    for (int ks = 0; ks < 2; ++ks) {
      bf16x8 af[4], bfr[4];
#pragma unroll
      for (int m = 0; m < 4; ++m) {
        int row = wm * 64 + m * 16 + laneM;
        af[m] = *(bf16x8*)&As[row * 64 + (((ks * 4 + kGrp) ^ (row & 7)) << 3)];
      }
#pragma unroll
      for (int n = 0; n < 4; ++n) {
        int row = wn * 64 + n * 16 + laneM;
        bfr[n] = *(bf16x8*)&Bs[row * 64 + (((ks * 4 + kGrp) ^ (row & 7)) << 3)];
      }
#pragma unroll
      for (int m = 0; m < 4; ++m)
#pragma unroll
        for (int n = 0; n < 4; ++n)
          acc[m][n] = __builtin_amdgcn_mfma_f32_16x16x32_bf16(af[m], bfr[n], acc[m][n], 0, 0, 0);
    }
  }

  float bvn[4];
#pragma unroll
  for (int n = 0; n < 4; ++n) bvn[n] = bv[wn * 64 + n * 16 + laneM];
#pragma unroll
  for (int m = 0; m < 4; ++m) {
#pragma unroll
    for (int r = 0; r < 4; ++r) {
      int row = bm + wm * 64 + m * 16 + kGrp * 4 + r;
      if (row < MVAL) {
#pragma unroll
        for (int n = 0; n < 4; ++n) {
          int col = wn * 64 + n * 16 + laneM;
          val[(size_t)row * 256 + col] = f2bf(acc[m][n][r] + bvn[n]);
        }
      }
    }
  }
}

// ---------------------------------------------------------------------------
// Kernel B: OFF = q @ W_off + b_off (2500,512); LOG = q @ W_attn + b_attn
// ---------------------------------------------------------------------------
__global__ __launch_bounds__(256) void k_qproj(
    const float* __restrict__ Q,
    const float* __restrict__ Woff, const float* __restrict__ boff,
    const float* __restrict__ Wattn, const float* __restrict__ battn,
    float* __restrict__ OFF, float* __restrict__ LOG)
{
  __shared__ float qs[8][256];
  const int t  = threadIdx.x;
  const int q0 = blockIdx.x * 8;
#pragma unroll
  for (int j = 0; j < 8; ++j) {
    int qi = q0 + j;
    qs[j][t] = (qi < NQ) ? Q[(size_t)qi * 256 + t] : 0.f;
  }
  __syncthreads();

#pragma unroll 1
  for (int pass = 0; pass < 3; ++pass) {
    const float* W  = (pass < 2) ? Woff : Wattn;
    const float* bb = (pass < 2) ? boff : battn;
    const int nc = (pass < 2) ? 512 : 256;
    const int c  = (pass == 1) ? (256 + t) : t;
    float acc[8];
    float bc = bb[c];
#pragma unroll
    for (int j = 0; j < 8; ++j) acc[j] = bc;
    for (int k = 0; k < 256; k += 4) {
      float w0 = W[(size_t)k * nc + c];
      float w1 = W[(size_t)(k + 1) * nc + c];
      float w2 = W[(size_t)(k + 2) * nc + c];
      float w3 = W[(size_t)(k + 3) * nc + c];
#pragma unroll
      for (int j = 0; j < 8; ++j) {
        float4 qv = *(const float4*)&qs[j][k];
        acc[j] += qv.x * w0 + qv.y * w1 + qv.z * w2 + qv.w * w3;
      }
    }
#pragma unroll
    for (int j = 0; j < 8; ++j) {
      int qi = q0 + j;
      if (qi < NQ) {
        if (pass < 2) OFF[(size_t)qi * 512 + c] = acc[j];
        else          LOG[(size_t)qi * 256 + c] = acc[j];
      }
    }
  }
}

// ---------------------------------------------------------------------------
// Kernel M: bev_mask -> valid[6*2500], on-device dtype detect (int32 vs u8).
// ---------------------------------------------------------------------------
__global__ __launch_bounds__(256) void k_maskvalid(
    const unsigned char* __restrict__ MSK,
    unsigned char* __restrict__ valid)
{
  __shared__ int s_u8;
  const int t = threadIdx.x;
  if (t == 0) s_u8 = 0;
  __syncthreads();
  if ((t & 3) && MSK[t]) atomicOr(&s_u8, 1);
  __syncthreads();
  const int isU8 = s_u8;

  const int i = blockIdx.x * 256 + t;
  if (i < NCAMS * NQ) {
    int any;
    if (isU8) {
      const unsigned char* p = MSK + (size_t)i * 4;
      any = p[0] | p[1] | p[2] | p[3];
    } else {
      const int* p = (const int*)MSK + (size_t)i * 4;
      any = p[0] | p[1] | p[2] | p[3];
    }
    valid[i] = any ? 1 : 0;
  }
}

// ---------------------------------------------------------------------------
// Kernel C (two-phase): coordinates computed ONCE per (h,lvl,p,cam) tuple by
// its owner thread into LDS; gather phase vectorized 4 d's per thread (uint2).
// Thread map phase1: t = h*32 + lvl*8 + p.
// Thread map phase2: h = t>>5, pp = (t>>3)&3, l8 = t&7 (d-quad = l8*4);
//   each thread covers lp = pp+4*it, it=0..7; shfl-reduce over pp.
// ---------------------------------------------------------------------------
__global__ __launch_bounds__(256) void k_sample(
    const unsigned short* __restrict__ val,   // (117360, 256) bf16
    const float* __restrict__ OFF, const float* __restrict__ LOG,
    const float* __restrict__ REF,            // (6,1,2500,4,2)
    const unsigned char* __restrict__ valid,  // (6,2500)
    float* __restrict__ slots)                // (2500,256)
{
  __shared__ int2  s_pack[4][NCAMS][256];  // {byte addr, weight bits} per corner
  __shared__ float s_off[512];
  __shared__ float s_ref[48];
  __shared__ int   s_valid[6];

  const int q = blockIdx.x;
  const int t = threadIdx.x;

  s_off[t]       = OFF[(size_t)q * 512 + t];
  s_off[t + 256] = OFF[(size_t)q * 512 + 256 + t];
  if (t < 48) s_ref[t] = REF[(size_t)(t >> 3) * (NQ * 8) + (size_t)q * 8 + (t & 7)];
  if (t < 6) s_valid[t] = valid[(size_t)t * NQ + q];

  // softmax over 32 logits per head (register-only; tuple t keeps its own aw)
  float logit = LOG[(size_t)q * 256 + t];
  float m = logit;
#pragma unroll
  for (int o = 16; o > 0; o >>= 1) m = fmaxf(m, __shfl_xor(m, o, 32));
  float e = __expf(logit - m);
  float s = e;
#pragma unroll
  for (int o = 16; o > 0; o >>= 1) s += __shfl_xor(s, o, 32);
  const float a = e / s;
  __syncthreads();

  // ---- phase 1: per-tuple corner addresses & weights ----
  {
    const int h1 = t >> 5, lp = t & 31, lvl = lp >> 3, p = lp & 7, z = p & 3;
    const int WW = 160 >> lvl;
    const int HH = (lvl < 3) ? (92 >> lvl) : 12;
    const int S  = (lvl == 0) ? 0 : (lvl == 1) ? 14720 : (lvl == 2) ? 18400 : 19320;
    const float Wf = (float)WW, Hf = (float)HH;
    const float ox = s_off[h1 * 64 + lp * 2];
    const float oy = s_off[h1 * 64 + lp * 2 + 1];
#pragma unroll 1
    for (int cam = 0; cam < NCAMS; ++cam) {
      if (!s_valid[cam]) continue;
      float rx = s_ref[cam * 8 + z * 2];
      float ry = s_ref[cam * 8 + z * 2 + 1];
      float x = rx * Wf + ox - 0.5f;
      float y = ry * Hf + oy - 0.5f;
      float x0f = floorf(x), y0f = floorf(y);
      float fx = x - x0f, fy = y - y0f;
      int x0 = (int)x0f, y0 = (int)y0f;
      int base = cam * LTOT + S;
#pragma unroll
      for (int dy = 0; dy < 2; ++dy) {
        int yi = y0 + dy;
        float wy = dy ? fy : 1.f - fy;
        int yc = min(max(yi, 0), HH - 1);
        bool vy = (yi >= 0) && (yi < HH);
#pragma unroll
        for (int dx = 0; dx < 2; ++dx) {
          int xi = x0 + dx;
          float wx = dx ? fx : 1.f - fx;
          int xc = min(max(xi, 0), WW - 1);
          bool vv = vy && (xi >= 0) && (xi < WW);
          float w = vv ? wx * wy * a : 0.f;
          int addr = (base + yc * WW + xc) * 512;  // byte offset of pixel row
          s_pack[dy * 2 + dx][cam][t] = make_int2(addr, __float_as_int(w));
        }
      }
    }
  }
  __syncthreads();

  // ---- phase 2: vectorized gather + FMA ----
  const int h = t >> 5, pp = (t >> 3) & 3, l8 = t & 7;
  const unsigned dconst = (unsigned)(h * 64 + l8 * 8);  // byte offset within pixel row
  const char* vb = (const char*)val;
  int nvalid = s_valid[0] + s_valid[1] + s_valid[2] + s_valid[3] + s_valid[4] + s_valid[5];
  float inv = 1.f / fmaxf((float)nvalid, 1.f);

  f32x4 acc = {0.f, 0.f, 0.f, 0.f};
#pragma unroll 1
  for (int cam = 0; cam < NCAMS; ++cam) {
    if (!s_valid[cam]) continue;
#pragma unroll
    for (int it = 0; it < 8; ++it) {
      const int idx = h * 32 + pp + it * 4;
      int2 pk0 = s_pack[0][cam][idx];
      int2 pk1 = s_pack[1][cam][idx];
      int2 pk2 = s_pack[2][cam][idx];
      int2 pk3 = s_pack[3][cam][idx];
      uint2 v0 = *(const uint2*)(vb + (size_t)((unsigned)pk0.x + dconst));
      uint2 v1 = *(const uint2*)(vb + (size_t)((unsigned)pk1.x + dconst));
      uint2 v2 = *(const uint2*)(vb + (size_t)((unsigned)pk2.x + dconst));
      uint2 v3 = *(const uint2*)(vb + (size_t)((unsigned)pk3.x + dconst));
      float w0 = __int_as_float(pk0.y), w1 = __int_as_float(pk1.y);
      float w2 = __int_as_float(pk2.y), w3 = __int_as_float(pk3.y);
      acc[0] += w0 * __uint_as_float(v0.x << 16);
      acc[1] += w0 * __uint_as_float(v0.x & 0xffff0000u);
      acc[2] += w0 * __uint_as_float(v0.y << 16);
      acc[3] += w0 * __uint_as_float(v0.y & 0xffff0000u);
      acc[0] += w1 * __uint_as_float(v1.x << 16);
      acc[1] += w1 * __uint_as_float(v1.x & 0xffff0000u);
      acc[2] += w1 * __uint_as_float(v1.y << 16);
      acc[3] += w1 * __uint_as_float(v1.y & 0xffff0000u);
      acc[0] += w2 * __uint_as_float(v2.x << 16);
      acc[1] += w2 * __uint_as_float(v2.x & 0xffff0000u);
      acc[2] += w2 * __uint_as_float(v2.y << 16);
      acc[3] += w2 * __uint_as_float(v2.y & 0xffff0000u);
      acc[0] += w3 * __uint_as_float(v3.x << 16);
      acc[1] += w3 * __uint_as_float(v3.x & 0xffff0000u);
      acc[2] += w3 * __uint_as_float(v3.y << 16);
      acc[3] += w3 * __uint_as_float(v3.y & 0xffff0000u);
    }
  }

  // reduce over pp (lane bits 3,4)
#pragma unroll
  for (int i = 0; i < 4; ++i) {
    acc[i] += __shfl_xor(acc[i], 8);
    acc[i] += __shfl_xor(acc[i], 16);
  }
  if (pp == 0) {
    float4 r = make_float4(acc[0] * inv, acc[1] * inv, acc[2] * inv, acc[3] * inv);
    *(float4*)&slots[(size_t)q * 256 + h * 32 + l8 * 4] = r;
  }
}

// ---------------------------------------------------------------------------
// Kernel D: out = slots @ W_out + b_out + query
// ---------------------------------------------------------------------------
__global__ __launch_bounds__(256) void k_outproj(
    const float* __restrict__ S, const float* __restrict__ Wout,
    const float* __restrict__ bout, const float* __restrict__ Q,
    float* __restrict__ out)
{
  __shared__ float ss[8][256];
  const int t  = threadIdx.x;
  const int q0 = blockIdx.x * 8;
#pragma unroll
  for (int j = 0; j < 8; ++j) {
    int qi = q0 + j;
    ss[j][t] = (qi < NQ) ? S[(size_t)qi * 256 + t] : 0.f;
  }
  __syncthreads();
  float acc[8] = {};
  for (int k = 0; k < 256; k += 4) {
    float w0 = Wout[(size_t)k * 256 + t];
    float w1 = Wout[(size_t)(k + 1) * 256 + t];
    float w2 = Wout[(size_t)(k + 2) * 256 + t];
    float w3 = Wout[(size_t)(k + 3) * 256 + t];
#pragma unroll
    for (int j = 0; j < 8; ++j) {
      float4 sv = *(const float4*)&ss[j][k];
      acc[j] += sv.x * w0 + sv.y * w1 + sv.z * w2 + sv.w * w3;
    }
  }
  float bc = bout[t];
#pragma unroll
  for (int j = 0; j < 8; ++j) {
    int qi = q0 + j;
    if (qi < NQ) out[(size_t)qi * 256 + t] = acc[j] + bc + Q[(size_t)qi * 256 + t];
  }
}

// ---------------------------------------------------------------------------
extern "C" void kernel_launch(void* const* d_in, const int* in_sizes, int n_in,
                              void* d_out, int out_size, void* d_ws, size_t ws_size,
                              hipStream_t stream) {
  const float* query     = (const float*)d_in[0];
  const float* key_feats = (const float*)d_in[1];
  const float* ref       = (const float*)d_in[2];
  const unsigned char* mask = (const unsigned char*)d_in[3];
  // d_in[4] = spatial_shapes (compile-time constants)
  const float* Wv    = (const float*)d_in[5];
  const float* bv    = (const float*)d_in[6];
  const float* Woff  = (const float*)d_in[7];
  const float* boff  = (const float*)d_in[8];
  const float* Wattn = (const float*)d_in[9];
  const float* battn = (const float*)d_in[10];
  const float* Wout  = (const float*)d_in[11];
  const float* bout  = (const float*)d_in[12];
  float* out = (float*)d_out;

  char* ws = (char*)d_ws;
  size_t off = 0;
  unsigned short* val = (unsigned short*)(ws + off); off += (size_t)MVAL * 256 * 2;
  unsigned short* WT  = (unsigned short*)(ws + off); off += 256 * 256 * 2;
  float* OFF   = (float*)(ws + off); off += (size_t)NQ * 512 * 4;
  float* LOG   = (float*)(ws + off); off += (size_t)NQ * 256 * 4;
  float* slots = (float*)(ws + off); off += (size_t)NQ * 256 * 4;
  unsigned char* valid = (unsigned char*)(ws + off); off += NCAMS * NQ;

  hipLaunchKernelGGL(k_wprep, dim3(256), dim3(256), 0, stream, Wv, WT);
  hipLaunchKernelGGL(k_valproj_mfma, dim3((MVAL + 127) / 128), dim3(512), 0, stream,
                     key_feats, WT, bv, val);
  hipLaunchKernelGGL(k_qproj, dim3((NQ + 7) / 8), dim3(256), 0, stream,
                     query, Woff, boff, Wattn, battn, OFF, LOG);
  hipLaunchKernelGGL(k_maskvalid, dim3((NCAMS * NQ + 255) / 256), dim3(256), 0, stream,
                     mask, valid);
  hipLaunchKernelGGL(k_sample, dim3(NQ), dim3(256), 0, stream,
                     val, OFF, LOG, ref, valid, slots);
  hipLaunchKernelGGL(k_outproj, dim3((NQ + 7) / 8), dim3(256), 0, stream,
                     slots, Wout, bout, query, out);
}

// Round 5
// 189.579 us; speedup vs baseline: 3.0293x; 1.4391x over previous
//
#include <hip/hip_runtime.h>
#include <hip/hip_bf16.h>
#include <cstdint>

#define NCAMS 6
#define NQ 2500
#define EMBED 256
#define HEADS 8
#define DHEAD 32
#define LTOT 19560
#define MVAL (NCAMS * LTOT) /* 117360 */

typedef __attribute__((ext_vector_type(8))) short bf16x8;
typedef __attribute__((ext_vector_type(4))) float f32x4;

__device__ __forceinline__ unsigned short f2bf(float f) {
  unsigned u = __float_as_uint(f);
  return (unsigned short)((u + 0x7fffu + ((u >> 16) & 1u)) >> 16);
}

// ---------------------------------------------------------------------------
// Kernel P: all weight transposes -> bf16, plus query -> bf16.
// grid 3780: [0,256) WT(Wvalue), [256,768) WTq cols 0-511 (Woff),
// [768,1024) WTq cols 512-767 (Wattn), [1024,1280) WoutT, [1280,3780) qbf.
// ---------------------------------------------------------------------------
__global__ __launch_bounds__(256) void k_prep(
    const float* __restrict__ Wv, const float* __restrict__ Woff,
    const float* __restrict__ Wattn, const float* __restrict__ Wout,
    const float* __restrict__ query,
    unsigned short* __restrict__ WT, unsigned short* __restrict__ WTq,
    unsigned short* __restrict__ WoutT, unsigned short* __restrict__ qbf)
{
  const int b = blockIdx.x, t = threadIdx.x;
  if (b < 256) {
    WT[(size_t)b * 256 + t] = f2bf(Wv[(size_t)t * 256 + b]);
  } else if (b < 768) {
    int c = b - 256;
    WTq[(size_t)c * 256 + t] = f2bf(Woff[(size_t)t * 512 + c]);
  } else if (b < 1024) {
    int c = b - 768;
    WTq[(size_t)(512 + c) * 256 + t] = f2bf(Wattn[(size_t)t * 256 + c]);
  } else if (b < 1280) {
    int c = b - 1024;
    WoutT[(size_t)c * 256 + t] = f2bf(Wout[(size_t)t * 256 + c]);
  } else {
    int q = b - 1280;
    qbf[(size_t)q * 256 + t] = f2bf(query[(size_t)q * 256 + t]);
  }
}

// ---------------------------------------------------------------------------
// Kernel A: val = bf16( key_feats @ W_value + b_value )  (MFMA, unchanged)
// ---------------------------------------------------------------------------
__global__ __launch_bounds__(512, 2) void k_valproj_mfma(
    const float* __restrict__ A,            // (117360, 256) f32
    const unsigned short* __restrict__ WT,  // (256 cols, 256 k) bf16
    const float* __restrict__ bv,           // (256,)
    unsigned short* __restrict__ val)       // (117360, 256) bf16
{
  __shared__ unsigned short As[128 * 64];
  __shared__ unsigned short Bs[256 * 64];
  const int t = threadIdx.x;
  const int lane = t & 63;
  const int wid = t >> 6;
  const int wm = wid >> 2, wn = wid & 3;
  const int laneM = lane & 15, kGrp = lane >> 4;
  const int bm = blockIdx.x * 128;

  const int aG = t & 15, aR0 = t >> 4;
  const int bC = t & 7,  bR0 = t >> 3;

  float4 aRegs[2][4];
  uint4  bRegs[2][4];
  f32x4  acc[4][4];
#pragma unroll
  for (int m = 0; m < 4; ++m)
#pragma unroll
    for (int n = 0; n < 4; ++n) acc[m][n] = {0.f, 0.f, 0.f, 0.f};

#pragma unroll
  for (int p = 0; p < 4; ++p) {
    int row = bm + aR0 + p * 32;
    aRegs[0][p] = (row < MVAL) ? *(const float4*)&A[(size_t)row * 256 + aG * 4]
                               : make_float4(0.f, 0.f, 0.f, 0.f);
    bRegs[0][p] = *(const uint4*)&WT[(size_t)(bR0 + p * 64) * 256 + bC * 8];
  }

#pragma unroll
  for (int kk = 0; kk < 4; ++kk) {
    const int cur = kk & 1, nxt = cur ^ 1;
    if (kk) __syncthreads();
#pragma unroll
    for (int p = 0; p < 4; ++p) {
      int row = aR0 + p * 32;
      int elem = row * 64 + (((aG >> 1) ^ (row & 7)) << 3) + (aG & 1) * 4;
      float4 a = aRegs[cur][p];
      uint2 u;
      u.x = (unsigned)f2bf(a.x) | ((unsigned)f2bf(a.y) << 16);
      u.y = (unsigned)f2bf(a.z) | ((unsigned)f2bf(a.w) << 16);
      *(uint2*)&As[elem] = u;
    }
#pragma unroll
    for (int p = 0; p < 4; ++p) {
      int row = bR0 + p * 64;
      int elem = row * 64 + ((bC ^ (row & 7)) << 3);
      *(uint4*)&Bs[elem] = bRegs[cur][p];
    }
    __syncthreads();
    if (kk < 3) {
      const int kn = (kk + 1) * 64;
#pragma unroll
      for (int p = 0; p < 4; ++p) {
        int row = bm + aR0 + p * 32;
        aRegs[nxt][p] = (row < MVAL)
            ? *(const float4*)&A[(size_t)row * 256 + kn + aG * 4]
            : make_float4(0.f, 0.f, 0.f, 0.f);
        bRegs[nxt][p] = *(const uint4*)&WT[(size_t)(bR0 + p * 64) * 256 + kn + bC * 8];
      }
    }
#pragma unroll
    for (int ks = 0; ks < 2; ++ks) {
      bf16x8 af[4], bfr[4];
#pragma unroll
      for (int m = 0; m < 4; ++m) {
        int row = wm * 64 + m * 16 + laneM;
        af[m] = *(bf16x8*)&As[row * 64 + (((ks * 4 + kGrp) ^ (row & 7)) << 3)];
      }
#pragma unroll
      for (int n = 0; n < 4; ++n) {
        int row = wn * 64 + n * 16 + laneM;
        bfr[n] = *(bf16x8*)&Bs[row * 64 + (((ks * 4 + kGrp) ^ (row & 7)) << 3)];
      }
#pragma unroll
      for (int m = 0; m < 4; ++m)
#pragma unroll
        for (int n = 0; n < 4; ++n)
          acc[m][n] = __builtin_amdgcn_mfma_f32_16x16x32_bf16(af[m], bfr[n], acc[m][n], 0, 0, 0);
    }
  }

  float bvn[4];
#pragma unroll
  for (int n = 0; n < 4; ++n) bvn[n] = bv[wn * 64 + n * 16 + laneM];
#pragma unroll
  for (int m = 0; m < 4; ++m) {
#pragma unroll
    for (int r = 0; r < 4; ++r) {
      int row = bm + wm * 64 + m * 16 + kGrp * 4 + r;
      if (row < MVAL) {
#pragma unroll
        for (int n = 0; n < 4; ++n) {
          int col = wn * 64 + n * 16 + laneM;
          val[(size_t)row * 256 + col] = f2bf(acc[m][n][r] + bvn[n]);
        }
      }
    }
  }
}

// ---------------------------------------------------------------------------
// Kernel G: generic small-M GEMM.  C(M,N) = A_bf16(M,256) @ BT_bf16(N,256)^T
//           + bias (split ba/bb at bsplit) [+ resid(M,256) if withResid]
// 256 threads = 4 waves (2x2), BM=128, BN=128, BK=64.
// ---------------------------------------------------------------------------
__global__ __launch_bounds__(256, 2) void k_gemm_small(
    const unsigned short* __restrict__ A,
    const unsigned short* __restrict__ BT,
    const float* __restrict__ ba, const float* __restrict__ bb, int bsplit,
    const float* __restrict__ resid,
    float* __restrict__ C, int M, int N, int withResid)
{
  __shared__ unsigned short As[128 * 64];
  __shared__ unsigned short Bs[128 * 64];
  const int t = threadIdx.x;
  const int lane = t & 63;
  const int wid = t >> 6;
  const int wm = wid >> 1, wn = wid & 1;
  const int laneM = lane & 15, kGrp = lane >> 4;
  const int bm = blockIdx.x * 128;
  const int bn = blockIdx.y * 128;

  const int aC = t & 7, aR0 = t >> 3;  // 8 x 16B chunks per row, 32 rows/pass

  uint4 aRegs[2][4];
  uint4 bRegs[2][4];
  f32x4 acc[4][4];
#pragma unroll
  for (int m = 0; m < 4; ++m)
#pragma unroll
    for (int n = 0; n < 4; ++n) acc[m][n] = {0.f, 0.f, 0.f, 0.f};

#pragma unroll
  for (int p = 0; p < 4; ++p) {
    int arow = bm + aR0 + p * 32;
    aRegs[0][p] = (arow < M) ? *(const uint4*)&A[(size_t)arow * 256 + aC * 8]
                             : make_uint4(0u, 0u, 0u, 0u);
    bRegs[0][p] = *(const uint4*)&BT[(size_t)(bn + aR0 + p * 32) * 256 + aC * 8];
  }

#pragma unroll
  for (int kk = 0; kk < 4; ++kk) {
    const int cur = kk & 1, nxt = cur ^ 1;
    if (kk) __syncthreads();
#pragma unroll
    for (int p = 0; p < 4; ++p) {
      int row = aR0 + p * 32;
      int elem = row * 64 + ((aC ^ (row & 7)) << 3);
      *(uint4*)&As[elem] = aRegs[cur][p];
      *(uint4*)&Bs[elem] = bRegs[cur][p];
    }
    __syncthreads();
    if (kk < 3) {
      const int kn = (kk + 1) * 64;
#pragma unroll
      for (int p = 0; p < 4; ++p) {
        int arow = bm + aR0 + p * 32;
        aRegs[nxt][p] = (arow < M)
            ? *(const uint4*)&A[(size_t)arow * 256 + kn + aC * 8]
            : make_uint4(0u, 0u, 0u, 0u);
        bRegs[nxt][p] = *(const uint4*)&BT[(size_t)(bn + aR0 + p * 32) * 256 + kn + aC * 8];
      }
    }
#pragma unroll
    for (int ks = 0; ks < 2; ++ks) {
      bf16x8 af[4], bfr[4];
#pragma unroll
      for (int m = 0; m < 4; ++m) {
        int row = wm * 64 + m * 16 + laneM;
        af[m] = *(bf16x8*)&As[row * 64 + (((ks * 4 + kGrp) ^ (row & 7)) << 3)];
      }
#pragma unroll
      for (int n = 0; n < 4; ++n) {
        int row = wn * 64 + n * 16 + laneM;
        bfr[n] = *(bf16x8*)&Bs[row * 64 + (((ks * 4 + kGrp) ^ (row & 7)) << 3)];
      }
#pragma unroll
      for (int m = 0; m < 4; ++m)
#pragma unroll
        for (int n = 0; n < 4; ++n)
          acc[m][n] = __builtin_amdgcn_mfma_f32_16x16x32_bf16(af[m], bfr[n], acc[m][n], 0, 0, 0);
    }
  }

  float bvn[4];
#pragma unroll
  for (int n = 0; n < 4; ++n) {
    int col = bn + wn * 64 + n * 16 + laneM;
    bvn[n] = (col < bsplit) ? ba[col] : bb[col - bsplit];
  }
#pragma unroll
  for (int m = 0; m < 4; ++m) {
#pragma unroll
    for (int r = 0; r < 4; ++r) {
      int row = bm + wm * 64 + m * 16 + kGrp * 4 + r;
      if (row < M) {
#pragma unroll
        for (int n = 0; n < 4; ++n) {
          int col = bn + wn * 64 + n * 16 + laneM;
          float v = acc[m][n][r] + bvn[n];
          if (withResid) v += resid[(size_t)row * 256 + col];
          C[(size_t)row * N + col] = v;
        }
      }
    }
  }
}

// ---------------------------------------------------------------------------
// Kernel M: bev_mask -> valid[6*2500], on-device dtype detect (int32 vs u8).
// ---------------------------------------------------------------------------
__global__ __launch_bounds__(256) void k_maskvalid(
    const unsigned char* __restrict__ MSK,
    unsigned char* __restrict__ valid)
{
  __shared__ int s_u8;
  const int t = threadIdx.x;
  if (t == 0) s_u8 = 0;
  __syncthreads();
  if ((t & 3) && MSK[t]) atomicOr(&s_u8, 1);
  __syncthreads();
  const int isU8 = s_u8;

  const int i = blockIdx.x * 256 + t;
  if (i < NCAMS * NQ) {
    int any;
    if (isU8) {
      const unsigned char* p = MSK + (size_t)i * 4;
      any = p[0] | p[1] | p[2] | p[3];
    } else {
      const int* p = (const int*)MSK + (size_t)i * 4;
      any = p[0] | p[1] | p[2] | p[3];
    }
    valid[i] = any ? 1 : 0;
  }
}

// ---------------------------------------------------------------------------
// Kernel C (two-phase sampling).  OFFLOG row = [OFF(512) | LOG(256)].
// Writes slots as bf16.
// ---------------------------------------------------------------------------
__global__ __launch_bounds__(256) void k_sample(
    const unsigned short* __restrict__ val,   // (117360, 256) bf16
    const float* __restrict__ OFFLOG,         // (2500, 768)
    const float* __restrict__ REF,            // (6,1,2500,4,2)
    const unsigned char* __restrict__ valid,  // (6,2500)
    unsigned short* __restrict__ slots)       // (2500,256) bf16
{
  __shared__ int2  s_pack[4][NCAMS][256];
  __shared__ float s_off[512];
  __shared__ float s_ref[48];
  __shared__ int   s_valid[6];

  const int q = blockIdx.x;
  const int t = threadIdx.x;

  s_off[t]       = OFFLOG[(size_t)q * 768 + t];
  s_off[t + 256] = OFFLOG[(size_t)q * 768 + 256 + t];
  if (t < 48) s_ref[t] = REF[(size_t)(t >> 3) * (NQ * 8) + (size_t)q * 8 + (t & 7)];
  if (t < 6) s_valid[t] = valid[(size_t)t * NQ + q];

  float logit = OFFLOG[(size_t)q * 768 + 512 + t];
  float m = logit;
#pragma unroll
  for (int o = 16; o > 0; o >>= 1) m = fmaxf(m, __shfl_xor(m, o, 32));
  float e = __expf(logit - m);
  float s = e;
#pragma unroll
  for (int o = 16; o > 0; o >>= 1) s += __shfl_xor(s, o, 32);
  const float a = e / s;
  __syncthreads();

  // ---- phase 1: per-tuple corner addresses & weights ----
  {
    const int h1 = t >> 5, lp = t & 31, lvl = lp >> 3, p = lp & 7, z = p & 3;
    const int WW = 160 >> lvl;
    const int HH = (lvl < 3) ? (92 >> lvl) : 12;
    const int S  = (lvl == 0) ? 0 : (lvl == 1) ? 14720 : (lvl == 2) ? 18400 : 19320;
    const float Wf = (float)WW, Hf = (float)HH;
    const float ox = s_off[h1 * 64 + lp * 2];
    const float oy = s_off[h1 * 64 + lp * 2 + 1];
#pragma unroll 1
    for (int cam = 0; cam < NCAMS; ++cam) {
      if (!s_valid[cam]) continue;
      float rx = s_ref[cam * 8 + z * 2];
      float ry = s_ref[cam * 8 + z * 2 + 1];
      float x = rx * Wf + ox - 0.5f;
      float y = ry * Hf + oy - 0.5f;
      float x0f = floorf(x), y0f = floorf(y);
      float fx = x - x0f, fy = y - y0f;
      int x0 = (int)x0f, y0 = (int)y0f;
      int base = cam * LTOT + S;
#pragma unroll
      for (int dy = 0; dy < 2; ++dy) {
        int yi = y0 + dy;
        float wy = dy ? fy : 1.f - fy;
        int yc = min(max(yi, 0), HH - 1);
        bool vy = (yi >= 0) && (yi < HH);
#pragma unroll
        for (int dx = 0; dx < 2; ++dx) {
          int xi = x0 + dx;
          float wx = dx ? fx : 1.f - fx;
          int xc = min(max(xi, 0), WW - 1);
          bool vv = vy && (xi >= 0) && (xi < WW);
          float w = vv ? wx * wy * a : 0.f;
          int addr = (base + yc * WW + xc) * 512;
          s_pack[dy * 2 + dx][cam][t] = make_int2(addr, __float_as_int(w));
        }
      }
    }
  }
  __syncthreads();

  // ---- phase 2: vectorized gather + FMA ----
  const int h = t >> 5, pp = (t >> 3) & 3, l8 = t & 7;
  const unsigned dconst = (unsigned)(h * 64 + l8 * 8);
  const char* vb = (const char*)val;
  int nvalid = s_valid[0] + s_valid[1] + s_valid[2] + s_valid[3] + s_valid[4] + s_valid[5];
  float inv = 1.f / fmaxf((float)nvalid, 1.f);

  f32x4 acc = {0.f, 0.f, 0.f, 0.f};
#pragma unroll 1
  for (int cam = 0; cam < NCAMS; ++cam) {
    if (!s_valid[cam]) continue;
#pragma unroll
    for (int it = 0; it < 8; ++it) {
      const int idx = h * 32 + pp + it * 4;
      int2 pk0 = s_pack[0][cam][idx];
      int2 pk1 = s_pack[1][cam][idx];
      int2 pk2 = s_pack[2][cam][idx];
      int2 pk3 = s_pack[3][cam][idx];
      uint2 v0 = *(const uint2*)(vb + (size_t)((unsigned)pk0.x + dconst));
      uint2 v1 = *(const uint2*)(vb + (size_t)((unsigned)pk1.x + dconst));
      uint2 v2 = *(const uint2*)(vb + (size_t)((unsigned)pk2.x + dconst));
      uint2 v3 = *(const uint2*)(vb + (size_t)((unsigned)pk3.x + dconst));
      float w0 = __int_as_float(pk0.y), w1 = __int_as_float(pk1.y);
      float w2 = __int_as_float(pk2.y), w3 = __int_as_float(pk3.y);
      acc[0] += w0 * __uint_as_float(v0.x << 16);
      acc[1] += w0 * __uint_as_float(v0.x & 0xffff0000u);
      acc[2] += w0 * __uint_as_float(v0.y << 16);
      acc[3] += w0 * __uint_as_float(v0.y & 0xffff0000u);
      acc[0] += w1 * __uint_as_float(v1.x << 16);
      acc[1] += w1 * __uint_as_float(v1.x & 0xffff0000u);
      acc[2] += w1 * __uint_as_float(v1.y << 16);
      acc[3] += w1 * __uint_as_float(v1.y & 0xffff0000u);
      acc[0] += w2 * __uint_as_float(v2.x << 16);
      acc[1] += w2 * __uint_as_float(v2.x & 0xffff0000u);
      acc[2] += w2 * __uint_as_float(v2.y << 16);
      acc[3] += w2 * __uint_as_float(v2.y & 0xffff0000u);
      acc[0] += w3 * __uint_as_float(v3.x << 16);
      acc[1] += w3 * __uint_as_float(v3.x & 0xffff0000u);
      acc[2] += w3 * __uint_as_float(v3.y << 16);
      acc[3] += w3 * __uint_as_float(v3.y & 0xffff0000u);
    }
  }

#pragma unroll
  for (int i = 0; i < 4; ++i) {
    acc[i] += __shfl_xor(acc[i], 8);
    acc[i] += __shfl_xor(acc[i], 16);
  }
  if (pp == 0) {
    uint2 r;
    r.x = (unsigned)f2bf(acc[0] * inv) | ((unsigned)f2bf(acc[1] * inv) << 16);
    r.y = (unsigned)f2bf(acc[2] * inv) | ((unsigned)f2bf(acc[3] * inv) << 16);
    *(uint2*)&slots[(size_t)q * 256 + h * 32 + l8 * 4] = r;
  }
}

// ---------------------------------------------------------------------------
extern "C" void kernel_launch(void* const* d_in, const int* in_sizes, int n_in,
                              void* d_out, int out_size, void* d_ws, size_t ws_size,
                              hipStream_t stream) {
  const float* query     = (const float*)d_in[0];
  const float* key_feats = (const float*)d_in[1];
  const float* ref       = (const float*)d_in[2];
  const unsigned char* mask = (const unsigned char*)d_in[3];
  // d_in[4] = spatial_shapes (compile-time constants)
  const float* Wv    = (const float*)d_in[5];
  const float* bv    = (const float*)d_in[6];
  const float* Woff  = (const float*)d_in[7];
  const float* boff  = (const float*)d_in[8];
  const float* Wattn = (const float*)d_in[9];
  const float* battn = (const float*)d_in[10];
  const float* Wout  = (const float*)d_in[11];
  const float* bout  = (const float*)d_in[12];
  float* out = (float*)d_out;

  char* ws = (char*)d_ws;
  size_t off = 0;
  unsigned short* val   = (unsigned short*)(ws + off); off += (size_t)MVAL * 256 * 2; // 60,088,320
  unsigned short* WT    = (unsigned short*)(ws + off); off += 256 * 256 * 2;
  unsigned short* WTq   = (unsigned short*)(ws + off); off += 768 * 256 * 2;
  unsigned short* WoutT = (unsigned short*)(ws + off); off += 256 * 256 * 2;
  unsigned short* qbf   = (unsigned short*)(ws + off); off += (size_t)NQ * 256 * 2;
  float* OFFLOG = (float*)(ws + off); off += (size_t)NQ * 768 * 4;
  unsigned short* slots = (unsigned short*)(ws + off); off += (size_t)NQ * 256 * 2;
  unsigned char* valid  = (unsigned char*)(ws + off); off += NCAMS * NQ;

  hipLaunchKernelGGL(k_prep, dim3(1280 + NQ), dim3(256), 0, stream,
                     Wv, Woff, Wattn, Wout, query, WT, WTq, WoutT, qbf);
  hipLaunchKernelGGL(k_valproj_mfma, dim3((MVAL + 127) / 128), dim3(512), 0, stream,
                     key_feats, WT, bv, val);
  hipLaunchKernelGGL(k_gemm_small, dim3((NQ + 127) / 128, 6), dim3(256), 0, stream,
                     qbf, WTq, boff, battn, 512, (const float*)nullptr, OFFLOG, NQ, 768, 0);
  hipLaunchKernelGGL(k_maskvalid, dim3((NCAMS * NQ + 255) / 256), dim3(256), 0, stream,
                     mask, valid);
  hipLaunchKernelGGL(k_sample, dim3(NQ), dim3(256), 0, stream,
                     val, OFFLOG, ref, valid, slots);
  hipLaunchKernelGGL(k_gemm_small, dim3((NQ + 127) / 128, 2), dim3(256), 0, stream,
                     slots, WoutT, bout, bout, 1 << 30, query, out, NQ, 256, 1);
}